// Round 16
// baseline (232.622 us; speedup 1.0000x reference)
//
#include <hip/hip_runtime.h>
#include <cmath>

// SplineNet: 2x SplineConv(D=128, deg-1 B-spline, 1-D pseudo) + linear head.
// Round 16: r15's proven agg (16B/lane dwordx4, 4 nodes/wave lockstep,
// inline static) + 32-node blocks (8 waves, 512 thr, launch_bounds(512,6)):
//  - B-fragment read once per 32 rows -> MFMA-phase L2 traffic halves
//  - 24-32 waves/CU during agg (vs 16) for gather latency hiding
// Canary: WRITE_SIZE must stay ~0.4/12.9MB (r11-r13 scratch regression).

typedef __attribute__((ext_vector_type(8))) short bf16x8;
typedef __attribute__((ext_vector_type(4))) float f32x4;

static inline int cdiv(int a, int b) { return (a + b - 1) / b; }

__device__ __forceinline__ float bf2f(unsigned short u) {
  unsigned v = ((unsigned)u) << 16;
  return __builtin_bit_cast(float, v);
}
__device__ __forceinline__ unsigned short f2bf(float f) {
  unsigned u = __builtin_bit_cast(unsigned, f);
  u += 0x7FFFu + ((u >> 16) & 1u);
  return (unsigned short)(u >> 16);
}
__device__ __forceinline__ float elu1(float v) {
  return v > 0.f ? v : (expf(v) - 1.f);
}

__global__ void hist_kernel(const int* __restrict__ ei, int E,
                            int* __restrict__ cnt) {
  int e = blockIdx.x * blockDim.x + threadIdx.x;
  if (e < E) atomicAdd(&cnt[ei[E + e]], 1);
}

// ---- three-phase device-wide exclusive scan over cnt[N] ----
__global__ void scan_partials_kernel(const int* __restrict__ cnt, int N,
                                     int* __restrict__ partials) {
  __shared__ int red[256];
  int base = blockIdx.x * 1024;
  int s = 0;
  for (int i = threadIdx.x; i < 1024; i += 256) {
    int idx = base + i;
    if (idx < N) s += cnt[idx];
  }
  red[threadIdx.x] = s;
  __syncthreads();
  for (int off = 128; off > 0; off >>= 1) {
    if (threadIdx.x < off) red[threadIdx.x] += red[threadIdx.x + off];
    __syncthreads();
  }
  if (threadIdx.x == 0) partials[blockIdx.x] = red[0];
}

__global__ void scan_pscan_kernel(const int* __restrict__ partials, int nb,
                                  int* __restrict__ pscan) {
  __shared__ int tmp[256];
  int t = threadIdx.x;
  int v = (t < nb) ? partials[t] : 0;
  tmp[t] = v;
  __syncthreads();
  for (int off = 1; off < 256; off <<= 1) {
    int u = (t >= off) ? tmp[t - off] : 0;
    __syncthreads();
    tmp[t] += u;
    __syncthreads();
  }
  pscan[t + 1] = tmp[t];
  if (t == 0) pscan[0] = 0;
}

__global__ void scan_apply_kernel(const int* __restrict__ cnt, int N,
                                  const int* __restrict__ pscan, int nb,
                                  int* __restrict__ rowptr, int* __restrict__ cursor) {
  __shared__ int tsum[256];
  int t = threadIdx.x;
  int base = blockIdx.x * 1024 + t * 4;
  int v0 = 0, v1 = 0, v2 = 0, v3 = 0;
  if (base + 0 < N) v0 = cnt[base + 0];
  if (base + 1 < N) v1 = cnt[base + 1];
  if (base + 2 < N) v2 = cnt[base + 2];
  if (base + 3 < N) v3 = cnt[base + 3];
  int s = v0 + v1 + v2 + v3;
  tsum[t] = s;
  __syncthreads();
  for (int off = 1; off < 256; off <<= 1) {
    int u = (t >= off) ? tsum[t - off] : 0;
    __syncthreads();
    tsum[t] += u;
    __syncthreads();
  }
  int excl = pscan[blockIdx.x] + tsum[t] - s;
  if (base + 0 < N) { rowptr[base + 0] = excl; cursor[base + 0] = excl; excl += v0; }
  if (base + 1 < N) { rowptr[base + 1] = excl; cursor[base + 1] = excl; excl += v1; }
  if (base + 2 < N) { rowptr[base + 2] = excl; cursor[base + 2] = excl; excl += v2; }
  if (base + 3 < N) { rowptr[base + 3] = excl; cursor[base + 3] = excl; excl += v3; }
  if (blockIdx.x == 0 && t == 0) rowptr[N] = pscan[nb];
}

// scatter edges into CSR order; pack (src, p) as int2
__global__ void scatter_kernel(const int* __restrict__ ei,
                               const float* __restrict__ ea, int E,
                               int* __restrict__ cursor, int2* __restrict__ es) {
  int e = blockIdx.x * blockDim.x + threadIdx.x;
  if (e < E) {
    int dst = ei[E + e];
    int pos = atomicAdd(&cursor[dst], 1);
    es[pos] = make_int2(ei[e], __float_as_int(ea[e]));
  }
}

// x (f32 [N][128]) -> compact bf16 xb[N][128]
__global__ void cvt_x_kernel(const float* __restrict__ x,
                             unsigned short* __restrict__ xb, int n4) {
  for (int i = blockIdx.x * blockDim.x + threadIdx.x; i < n4;
       i += gridDim.x * blockDim.x) {
    float4 v = ((const float4*)x)[i];
    ushort4 o;
    o.x = f2bf(v.x); o.y = f2bf(v.y); o.z = f2bf(v.z); o.w = f2bf(v.w);
    ((ushort4*)xb)[i] = o;
  }
}

// Build B in MFMA-fragment order: BtF[frag G][lane][8] where G = ks*8+ni,
// col = ni*16+(lane&15), k = ks*32+(lane>>4)*8+j ; B[k][col] = k<KD?W:root.
__global__ void build_btf_kernel(const float* __restrict__ W,
                                 const float* __restrict__ root,
                                 unsigned short* __restrict__ BtF, int KD, int KT) {
  int idx = blockIdx.x * blockDim.x + threadIdx.x;
  if (idx >= 128 * KT) return;
  int G = idx >> 9;
  int r = idx & 511;
  int lane = r >> 3;
  int j = r & 7;
  int ks = G >> 3;
  int ni = G & 7;
  int col = ni * 16 + (lane & 15);
  int k = ks * 32 + (lane >> 4) * 8 + j;
  float v = (k < KD) ? W[(size_t)k * 128 + col] : root[(size_t)(k - KD) * 128 + col];
  BtF[idx] = f2bf(v);
}

// FUSED layer: block = 8 waves = 32 nodes. Agg identical to r15 (wave = 4
// nodes simultaneously, 16 lanes/node, 16B dwordx4 gathers, lockstep over
// max-degree, masked slots v=-2). MFMA: wave w = n-frag w x 2 m-frags
// (rows 0-15, 16-31) -> each B-frag read ONCE per block.
template <int K, int KT, bool FINAL>
__global__ __launch_bounds__(512, 6) void fused_layer(
    const unsigned short* __restrict__ Xc,
    const int* __restrict__ rowptr, const int2* __restrict__ es,
    const unsigned short* __restrict__ BtF,
    const float* __restrict__ bias,
    unsigned short* __restrict__ Hout,
    const float* __restrict__ Wm, const float* __restrict__ bm,
    float* __restrict__ FOut, int N) {
  constexpr int LDK = KT + 8;          // pad keeps rows 16B-aligned, staggers banks
  constexpr int NKS = KT / 32;
  __shared__ unsigned short Asub[32][LDK];

  const int w = threadIdx.x >> 6;
  const int lane = threadIdx.x & 63;
  const int lr = lane & 15;
  const int kg = lane >> 4;
  const int node0 = blockIdx.x * 32;

  // ---- agg phase (r15-identical inner loop) ----
  const int g = lane >> 4;        // node sub-index within wave (0..3)
  const int d16 = lane & 15;      // dim-block: dims d16*8 .. d16*8+7
  const int r = w * 4 + g;        // row in block tile (0..31)
  const int node = min(node0 + r, N - 1);
  const int beg = rowptr[node];
  const int end = rowptr[node + 1];
  const int deg = end - beg;

  float acc[K][8];
#pragma unroll
  for (int k = 0; k < K; ++k)
#pragma unroll
    for (int j = 0; j < 8; ++j) acc[k][j] = 0.f;

  const int mx = max(max(__shfl(deg, 0), __shfl(deg, 16)),
                     max(__shfl(deg, 32), __shfl(deg, 48)));
  const int lastc = max(end - 1, 0);

  for (int s0 = 0; s0 < mx; s0 += 4) {
    int2 sp[4];
#pragma unroll
    for (int t = 0; t < 4; ++t) sp[t] = es[min(beg + s0 + t, lastc)];
    uint4 rv[4];
#pragma unroll
    for (int t = 0; t < 4; ++t)
      rv[t] = *(const uint4*)(Xc + (size_t)sp[t].x * 128 + d16 * 8);
#pragma unroll
    for (int t = 0; t < 4; ++t) {
      const bool ok = (s0 + t) < deg;
      const float v = ok ? __int_as_float(sp[t].y) * (float)(K - 1) : -2.f;
      float x[8];
      x[0] = __builtin_bit_cast(float, rv[t].x << 16);
      x[1] = __builtin_bit_cast(float, rv[t].x & 0xffff0000u);
      x[2] = __builtin_bit_cast(float, rv[t].y << 16);
      x[3] = __builtin_bit_cast(float, rv[t].y & 0xffff0000u);
      x[4] = __builtin_bit_cast(float, rv[t].z << 16);
      x[5] = __builtin_bit_cast(float, rv[t].z & 0xffff0000u);
      x[6] = __builtin_bit_cast(float, rv[t].w << 16);
      x[7] = __builtin_bit_cast(float, rv[t].w & 0xffff0000u);
#pragma unroll
      for (int k = 0; k < K; ++k) {
        const float wk = fmaxf(1.f - fabsf(v - (float)k), 0.f);
#pragma unroll
        for (int j = 0; j < 8; ++j) acc[k][j] = fmaf(wk, x[j], acc[k][j]);
      }
    }
  }

  const float sc = 1.f / fmaxf((float)deg, 1.f);
#pragma unroll
  for (int k = 0; k < K; ++k) {
    uint4 ov;
    ov.x = (unsigned)f2bf(acc[k][0] * sc) | ((unsigned)f2bf(acc[k][1] * sc) << 16);
    ov.y = (unsigned)f2bf(acc[k][2] * sc) | ((unsigned)f2bf(acc[k][3] * sc) << 16);
    ov.z = (unsigned)f2bf(acc[k][4] * sc) | ((unsigned)f2bf(acc[k][5] * sc) << 16);
    ov.w = (unsigned)f2bf(acc[k][6] * sc) | ((unsigned)f2bf(acc[k][7] * sc) << 16);
    *(uint4*)&Asub[r][k * 128 + d16 * 8] = ov;
  }
  // own row (root term): coalesced 16B copy
  uint4 ownv = *(const uint4*)(Xc + (size_t)node * 128 + d16 * 8);
  *(uint4*)&Asub[r][K * 128 + d16 * 8] = ownv;
  __syncthreads();

  // ---- MFMA phase: wave w = n-frag w (cols w*16..+15) x 2 m-frags ----
  const int ni = w;
  f32x4 acc0 = {0.f, 0.f, 0.f, 0.f};
  f32x4 acc1 = {0.f, 0.f, 0.f, 0.f};
#pragma unroll
  for (int ks = 0; ks < NKS; ++ks) {
    bf16x8 b = *(const bf16x8*)(BtF + (size_t)(ks * 8 + ni) * 512 + lane * 8);
    bf16x8 a0 = *(const bf16x8*)&Asub[lr][ks * 32 + kg * 8];
    bf16x8 a1 = *(const bf16x8*)&Asub[16 + lr][ks * 32 + kg * 8];
    acc0 = __builtin_amdgcn_mfma_f32_16x16x32_bf16(a0, b, acc0, 0, 0, 0);
    acc1 = __builtin_amdgcn_mfma_f32_16x16x32_bf16(a1, b, acc1, 0, 0, 0);
  }

  const float bv = bias[ni * 16 + lr];

  if constexpr (!FINAL) {
#pragma unroll
    for (int mf = 0; mf < 2; ++mf) {
      f32x4 a = mf ? acc1 : acc0;
#pragma unroll
      for (int rr = 0; rr < 4; ++rr) {
        int onode = node0 + mf * 16 + kg * 4 + rr;
        if (onode < N) {
          float h = elu1(a[rr] + bv);
          Hout[(size_t)onode * 128 + ni * 16 + lr] = f2bf(h);
        }
      }
    }
  } else {
    __shared__ float hred[8][32][2];
    float2 wv = *(const float2*)&Wm[(ni * 16 + lr) * 2];
#pragma unroll
    for (int mf = 0; mf < 2; ++mf) {
      f32x4 a = mf ? acc1 : acc0;
#pragma unroll
      for (int rr = 0; rr < 4; ++rr) {
        float h = elu1(a[rr] + bv);
        float t0 = h * wv.x;
        float t1 = h * wv.y;
#pragma unroll
        for (int off = 8; off > 0; off >>= 1) {
          t0 += __shfl_down(t0, off);
          t1 += __shfl_down(t1, off);
        }
        if (lr == 0) {
          hred[w][mf * 16 + kg * 4 + rr][0] = t0;
          hred[w][mf * 16 + kg * 4 + rr][1] = t1;
        }
      }
    }
    __syncthreads();
    if (threadIdx.x < 64) {
      int row = threadIdx.x >> 1;
      int c = threadIdx.x & 1;
      int onode = node0 + row;
      if (onode < N) {
        float s = bm[c];
#pragma unroll
        for (int ww = 0; ww < 8; ++ww) s += hred[ww][row][c];
        FOut[(size_t)onode * 2 + c] = fmaxf(s, 0.f);
      }
    }
  }
}

extern "C" void kernel_launch(void* const* d_in, const int* in_sizes, int n_in,
                              void* d_out, int out_size, void* d_ws, size_t ws_size,
                              hipStream_t stream) {
  const float* x = (const float*)d_in[0];
  const int* ei = (const int*)d_in[1];
  const float* ea = (const float*)d_in[2];
  const float* W1 = (const float*)d_in[3];
  const float* root1 = (const float*)d_in[4];
  const float* b1 = (const float*)d_in[5];
  const float* W2 = (const float*)d_in[6];
  const float* root2 = (const float*)d_in[7];
  const float* b2 = (const float*)d_in[8];
  const float* Wm = (const float*)d_in[9];
  const float* bm = (const float*)d_in[10];
  const int N = in_sizes[0] / 128;
  const int E = in_sizes[2];
  const int KT1 = 512, KT2 = 768;
  const int nb = cdiv(N, 1024);

  char* base = (char*)d_ws;
  size_t off = 0;
  auto alloc = [&](size_t bytes) -> void* {
    void* p = base + off;
    off += (bytes + 255) & ~(size_t)255;
    return p;
  };
  int* cnt = (int*)alloc((size_t)N * 4);
  int* rowptr = (int*)alloc((size_t)(N + 1) * 4);
  int* cursor = (int*)alloc((size_t)N * 4);
  int* partials = (int*)alloc(256 * 4);
  int* pscan = (int*)alloc(257 * 4);
  int2* es = (int2*)alloc((size_t)E * 8);
  unsigned short* xb = (unsigned short*)alloc((size_t)N * 128 * 2);
  unsigned short* h1 = (unsigned short*)alloc((size_t)N * 128 * 2);
  unsigned short* BtF1 = (unsigned short*)alloc((size_t)128 * KT1 * 2);
  unsigned short* BtF2 = (unsigned short*)alloc((size_t)128 * KT2 * 2);
  (void)ws_size; (void)n_in; (void)out_size;

  // CSR build (dst bins)
  hipMemsetAsync(cnt, 0, (size_t)N * 4, stream);
  hist_kernel<<<cdiv(E, 256), 256, 0, stream>>>(ei, E, cnt);
  scan_partials_kernel<<<nb, 256, 0, stream>>>(cnt, N, partials);
  scan_pscan_kernel<<<1, 256, 0, stream>>>(partials, nb, pscan);
  scan_apply_kernel<<<nb, 256, 0, stream>>>(cnt, N, pscan, nb, rowptr, cursor);
  scatter_kernel<<<cdiv(E, 256), 256, 0, stream>>>(ei, ea, E, cursor, es);

  // weights -> fragment-order bf16
  build_btf_kernel<<<cdiv(128 * KT1, 256), 256, 0, stream>>>(W1, root1, BtF1, 384, KT1);
  build_btf_kernel<<<cdiv(128 * KT2, 256), 256, 0, stream>>>(W2, root2, BtF2, 640, KT2);

  // x -> compact bf16 xb
  cvt_x_kernel<<<2048, 256, 0, stream>>>(x, xb, N * 32);

  const int nblk = cdiv(N, 32);
  // layer 1 (K=3): fused agg+GEMM -> compact h1
  fused_layer<3, 512, false><<<nblk, 512, 0, stream>>>(
      xb, rowptr, es, BtF1, b1, h1, nullptr, nullptr, nullptr, N);
  // layer 2 (K=5): fused agg+GEMM+head -> out
  fused_layer<5, 768, true><<<nblk, 512, 0, stream>>>(
      h1, rowptr, es, BtF2, b2, nullptr, Wm, bm, (float*)d_out, N);
}

// Round 17
// 190.151 us; speedup vs baseline: 1.2234x; 1.2234x over previous
//
#include <hip/hip_runtime.h>
#include <cmath>

// SplineNet: 2x SplineConv(D=128, deg-1 B-spline, 1-D pseudo) + linear head.
// Round 17: 32-node tile at 256 threads (512-thread shape spills: r11/r12/r16
// all show VGPR=40 + scratch; 256-thread allocates cleanly). Wave runs r15's
// 4-node lockstep agg TWICE (rows w*8+ii*4+g); MFMA wave = 2 n-frags x
// 2 m-frags with named accumulators -> each B-frag read once per 32 rows
// (half of r15's per-row B traffic). Canary: WRITE_SIZE 0.39/12.9MB.

typedef __attribute__((ext_vector_type(8))) short bf16x8;
typedef __attribute__((ext_vector_type(4))) float f32x4;

static inline int cdiv(int a, int b) { return (a + b - 1) / b; }

__device__ __forceinline__ float bf2f(unsigned short u) {
  unsigned v = ((unsigned)u) << 16;
  return __builtin_bit_cast(float, v);
}
__device__ __forceinline__ unsigned short f2bf(float f) {
  unsigned u = __builtin_bit_cast(unsigned, f);
  u += 0x7FFFu + ((u >> 16) & 1u);
  return (unsigned short)(u >> 16);
}
__device__ __forceinline__ float elu1(float v) {
  return v > 0.f ? v : (expf(v) - 1.f);
}

__global__ void hist_kernel(const int* __restrict__ ei, int E,
                            int* __restrict__ cnt) {
  int e = blockIdx.x * blockDim.x + threadIdx.x;
  if (e < E) atomicAdd(&cnt[ei[E + e]], 1);
}

// ---- three-phase device-wide exclusive scan over cnt[N] ----
__global__ void scan_partials_kernel(const int* __restrict__ cnt, int N,
                                     int* __restrict__ partials) {
  __shared__ int red[256];
  int base = blockIdx.x * 1024;
  int s = 0;
  for (int i = threadIdx.x; i < 1024; i += 256) {
    int idx = base + i;
    if (idx < N) s += cnt[idx];
  }
  red[threadIdx.x] = s;
  __syncthreads();
  for (int off = 128; off > 0; off >>= 1) {
    if (threadIdx.x < off) red[threadIdx.x] += red[threadIdx.x + off];
    __syncthreads();
  }
  if (threadIdx.x == 0) partials[blockIdx.x] = red[0];
}

__global__ void scan_pscan_kernel(const int* __restrict__ partials, int nb,
                                  int* __restrict__ pscan) {
  __shared__ int tmp[256];
  int t = threadIdx.x;
  int v = (t < nb) ? partials[t] : 0;
  tmp[t] = v;
  __syncthreads();
  for (int off = 1; off < 256; off <<= 1) {
    int u = (t >= off) ? tmp[t - off] : 0;
    __syncthreads();
    tmp[t] += u;
    __syncthreads();
  }
  pscan[t + 1] = tmp[t];
  if (t == 0) pscan[0] = 0;
}

__global__ void scan_apply_kernel(const int* __restrict__ cnt, int N,
                                  const int* __restrict__ pscan, int nb,
                                  int* __restrict__ rowptr, int* __restrict__ cursor) {
  __shared__ int tsum[256];
  int t = threadIdx.x;
  int base = blockIdx.x * 1024 + t * 4;
  int v0 = 0, v1 = 0, v2 = 0, v3 = 0;
  if (base + 0 < N) v0 = cnt[base + 0];
  if (base + 1 < N) v1 = cnt[base + 1];
  if (base + 2 < N) v2 = cnt[base + 2];
  if (base + 3 < N) v3 = cnt[base + 3];
  int s = v0 + v1 + v2 + v3;
  tsum[t] = s;
  __syncthreads();
  for (int off = 1; off < 256; off <<= 1) {
    int u = (t >= off) ? tsum[t - off] : 0;
    __syncthreads();
    tsum[t] += u;
    __syncthreads();
  }
  int excl = pscan[blockIdx.x] + tsum[t] - s;
  if (base + 0 < N) { rowptr[base + 0] = excl; cursor[base + 0] = excl; excl += v0; }
  if (base + 1 < N) { rowptr[base + 1] = excl; cursor[base + 1] = excl; excl += v1; }
  if (base + 2 < N) { rowptr[base + 2] = excl; cursor[base + 2] = excl; excl += v2; }
  if (base + 3 < N) { rowptr[base + 3] = excl; cursor[base + 3] = excl; excl += v3; }
  if (blockIdx.x == 0 && t == 0) rowptr[N] = pscan[nb];
}

// scatter edges into CSR order; pack (src, p) as int2
__global__ void scatter_kernel(const int* __restrict__ ei,
                               const float* __restrict__ ea, int E,
                               int* __restrict__ cursor, int2* __restrict__ es) {
  int e = blockIdx.x * blockDim.x + threadIdx.x;
  if (e < E) {
    int dst = ei[E + e];
    int pos = atomicAdd(&cursor[dst], 1);
    es[pos] = make_int2(ei[e], __float_as_int(ea[e]));
  }
}

// x (f32 [N][128]) -> compact bf16 xb[N][128]
__global__ void cvt_x_kernel(const float* __restrict__ x,
                             unsigned short* __restrict__ xb, int n4) {
  for (int i = blockIdx.x * blockDim.x + threadIdx.x; i < n4;
       i += gridDim.x * blockDim.x) {
    float4 v = ((const float4*)x)[i];
    ushort4 o;
    o.x = f2bf(v.x); o.y = f2bf(v.y); o.z = f2bf(v.z); o.w = f2bf(v.w);
    ((ushort4*)xb)[i] = o;
  }
}

// Build B in MFMA-fragment order: BtF[frag G][lane][8] where G = ks*8+ni,
// col = ni*16+(lane&15), k = ks*32+(lane>>4)*8+j ; B[k][col] = k<KD?W:root.
__global__ void build_btf_kernel(const float* __restrict__ W,
                                 const float* __restrict__ root,
                                 unsigned short* __restrict__ BtF, int KD, int KT) {
  int idx = blockIdx.x * blockDim.x + threadIdx.x;
  if (idx >= 128 * KT) return;
  int G = idx >> 9;
  int r = idx & 511;
  int lane = r >> 3;
  int j = r & 7;
  int ks = G >> 3;
  int ni = G & 7;
  int col = ni * 16 + (lane & 15);
  int k = ks * 32 + (lane >> 4) * 8 + j;
  float v = (k < KD) ? W[(size_t)k * 128 + col] : root[(size_t)(k - KD) * 128 + col];
  BtF[idx] = f2bf(v);
}

// FUSED layer: block = 4 waves = 32 nodes (256 thr). Agg: wave runs the
// r15 4-node lockstep loop twice (16 lanes/node, 16B dwordx4 gathers).
// MFMA: wave w = n-frags {2w,2w+1} x m-frags {rows 0-15, 16-31}; each
// B-frag read once per block.
template <int K, int KT, bool FINAL>
__global__ __launch_bounds__(256, 4) void fused_layer(
    const unsigned short* __restrict__ Xc,
    const int* __restrict__ rowptr, const int2* __restrict__ es,
    const unsigned short* __restrict__ BtF,
    const float* __restrict__ bias,
    unsigned short* __restrict__ Hout,
    const float* __restrict__ Wm, const float* __restrict__ bm,
    float* __restrict__ FOut, int N) {
  constexpr int LDK = KT + 8;          // pad keeps rows 16B-aligned, staggers banks
  constexpr int NKS = KT / 32;
  __shared__ unsigned short Asub[32][LDK];

  const int w = threadIdx.x >> 6;
  const int lane = threadIdx.x & 63;
  const int lr = lane & 15;
  const int kg = lane >> 4;
  const int node0 = blockIdx.x * 32;

  // ---- agg phase: wave w fills rows w*8 .. w*8+7 (two 4-node passes) ----
  const int g = lane >> 4;        // node sub-index within wave (0..3)
  const int d16 = lane & 15;      // dim-block: dims d16*8 .. d16*8+7

  for (int ii = 0; ii < 2; ++ii) {
    const int r = w * 8 + ii * 4 + g;
    const int node = min(node0 + r, N - 1);
    const int beg = rowptr[node];
    const int end = rowptr[node + 1];
    const int deg = end - beg;

    float acc[K][8];
#pragma unroll
    for (int k = 0; k < K; ++k)
#pragma unroll
      for (int j = 0; j < 8; ++j) acc[k][j] = 0.f;

    const int mx = max(max(__shfl(deg, 0), __shfl(deg, 16)),
                       max(__shfl(deg, 32), __shfl(deg, 48)));
    const int lastc = max(end - 1, 0);

    for (int s0 = 0; s0 < mx; s0 += 4) {
      int2 sp[4];
#pragma unroll
      for (int t = 0; t < 4; ++t) sp[t] = es[min(beg + s0 + t, lastc)];
      uint4 rv[4];
#pragma unroll
      for (int t = 0; t < 4; ++t)
        rv[t] = *(const uint4*)(Xc + (size_t)sp[t].x * 128 + d16 * 8);
#pragma unroll
      for (int t = 0; t < 4; ++t) {
        const bool ok = (s0 + t) < deg;
        const float v = ok ? __int_as_float(sp[t].y) * (float)(K - 1) : -2.f;
        float x[8];
        x[0] = __builtin_bit_cast(float, rv[t].x << 16);
        x[1] = __builtin_bit_cast(float, rv[t].x & 0xffff0000u);
        x[2] = __builtin_bit_cast(float, rv[t].y << 16);
        x[3] = __builtin_bit_cast(float, rv[t].y & 0xffff0000u);
        x[4] = __builtin_bit_cast(float, rv[t].z << 16);
        x[5] = __builtin_bit_cast(float, rv[t].z & 0xffff0000u);
        x[6] = __builtin_bit_cast(float, rv[t].w << 16);
        x[7] = __builtin_bit_cast(float, rv[t].w & 0xffff0000u);
#pragma unroll
        for (int k = 0; k < K; ++k) {
          const float wk = fmaxf(1.f - fabsf(v - (float)k), 0.f);
#pragma unroll
          for (int j = 0; j < 8; ++j) acc[k][j] = fmaf(wk, x[j], acc[k][j]);
        }
      }
    }

    const float sc = 1.f / fmaxf((float)deg, 1.f);
#pragma unroll
    for (int k = 0; k < K; ++k) {
      uint4 ov;
      ov.x = (unsigned)f2bf(acc[k][0] * sc) | ((unsigned)f2bf(acc[k][1] * sc) << 16);
      ov.y = (unsigned)f2bf(acc[k][2] * sc) | ((unsigned)f2bf(acc[k][3] * sc) << 16);
      ov.z = (unsigned)f2bf(acc[k][4] * sc) | ((unsigned)f2bf(acc[k][5] * sc) << 16);
      ov.w = (unsigned)f2bf(acc[k][6] * sc) | ((unsigned)f2bf(acc[k][7] * sc) << 16);
      *(uint4*)&Asub[r][k * 128 + d16 * 8] = ov;
    }
    // own row (root term): coalesced 16B copy
    uint4 ownv = *(const uint4*)(Xc + (size_t)node * 128 + d16 * 8);
    *(uint4*)&Asub[r][K * 128 + d16 * 8] = ownv;
  }
  __syncthreads();

  // ---- MFMA phase: wave w = n-frags {2w,2w+1} x m-frags {0,1} ----
  const int ni0 = w * 2;
  f32x4 acc00 = {0.f, 0.f, 0.f, 0.f};   // m-frag 0 (rows 0-15), n-frag ni0
  f32x4 acc01 = {0.f, 0.f, 0.f, 0.f};   // m-frag 0, n-frag ni0+1
  f32x4 acc10 = {0.f, 0.f, 0.f, 0.f};   // m-frag 1 (rows 16-31), n-frag ni0
  f32x4 acc11 = {0.f, 0.f, 0.f, 0.f};   // m-frag 1, n-frag ni0+1
#pragma unroll
  for (int ks = 0; ks < NKS; ++ks) {
    bf16x8 b0 = *(const bf16x8*)(BtF + (size_t)(ks * 8 + ni0) * 512 + lane * 8);
    bf16x8 b1 = *(const bf16x8*)(BtF + (size_t)(ks * 8 + ni0 + 1) * 512 + lane * 8);
    bf16x8 a0 = *(const bf16x8*)&Asub[lr][ks * 32 + kg * 8];
    bf16x8 a1 = *(const bf16x8*)&Asub[16 + lr][ks * 32 + kg * 8];
    acc00 = __builtin_amdgcn_mfma_f32_16x16x32_bf16(a0, b0, acc00, 0, 0, 0);
    acc01 = __builtin_amdgcn_mfma_f32_16x16x32_bf16(a0, b1, acc01, 0, 0, 0);
    acc10 = __builtin_amdgcn_mfma_f32_16x16x32_bf16(a1, b0, acc10, 0, 0, 0);
    acc11 = __builtin_amdgcn_mfma_f32_16x16x32_bf16(a1, b1, acc11, 0, 0, 0);
  }

  float bv[2];
#pragma unroll
  for (int j = 0; j < 2; ++j) bv[j] = bias[(ni0 + j) * 16 + lr];

  if constexpr (!FINAL) {
#pragma unroll
    for (int rr = 0; rr < 4; ++rr) {
      int onode0 = node0 + kg * 4 + rr;          // m-frag 0
      int onode1 = node0 + 16 + kg * 4 + rr;     // m-frag 1
      if (onode0 < N) {
        float h0 = elu1(acc00[rr] + bv[0]);
        float h1 = elu1(acc01[rr] + bv[1]);
        Hout[(size_t)onode0 * 128 + ni0 * 16 + lr] = f2bf(h0);
        Hout[(size_t)onode0 * 128 + (ni0 + 1) * 16 + lr] = f2bf(h1);
      }
      if (onode1 < N) {
        float h0 = elu1(acc10[rr] + bv[0]);
        float h1 = elu1(acc11[rr] + bv[1]);
        Hout[(size_t)onode1 * 128 + ni0 * 16 + lr] = f2bf(h0);
        Hout[(size_t)onode1 * 128 + (ni0 + 1) * 16 + lr] = f2bf(h1);
      }
    }
  } else {
    __shared__ float hred[4][32][2];
    float wm0[2], wm1[2];
#pragma unroll
    for (int j = 0; j < 2; ++j) {
      float2 wv = *(const float2*)&Wm[((ni0 + j) * 16 + lr) * 2];
      wm0[j] = wv.x; wm1[j] = wv.y;
    }
#pragma unroll
    for (int rr = 0; rr < 4; ++rr) {
      // m-frag 0
      {
        float h0 = elu1(acc00[rr] + bv[0]);
        float h1 = elu1(acc01[rr] + bv[1]);
        float t0 = fmaf(h0, wm0[0], h1 * wm0[1]);
        float t1 = fmaf(h0, wm1[0], h1 * wm1[1]);
#pragma unroll
        for (int off = 8; off > 0; off >>= 1) {
          t0 += __shfl_down(t0, off);
          t1 += __shfl_down(t1, off);
        }
        if (lr == 0) {
          hred[w][kg * 4 + rr][0] = t0;
          hred[w][kg * 4 + rr][1] = t1;
        }
      }
      // m-frag 1
      {
        float h0 = elu1(acc10[rr] + bv[0]);
        float h1 = elu1(acc11[rr] + bv[1]);
        float t0 = fmaf(h0, wm0[0], h1 * wm0[1]);
        float t1 = fmaf(h0, wm1[0], h1 * wm1[1]);
#pragma unroll
        for (int off = 8; off > 0; off >>= 1) {
          t0 += __shfl_down(t0, off);
          t1 += __shfl_down(t1, off);
        }
        if (lr == 0) {
          hred[w][16 + kg * 4 + rr][0] = t0;
          hred[w][16 + kg * 4 + rr][1] = t1;
        }
      }
    }
    __syncthreads();
    if (threadIdx.x < 64) {
      int row = threadIdx.x >> 1;
      int c = threadIdx.x & 1;
      int onode = node0 + row;
      if (onode < N) {
        float s = hred[0][row][c] + hred[1][row][c] + hred[2][row][c] +
                  hred[3][row][c] + bm[c];
        FOut[(size_t)onode * 2 + c] = fmaxf(s, 0.f);
      }
    }
  }
}

extern "C" void kernel_launch(void* const* d_in, const int* in_sizes, int n_in,
                              void* d_out, int out_size, void* d_ws, size_t ws_size,
                              hipStream_t stream) {
  const float* x = (const float*)d_in[0];
  const int* ei = (const int*)d_in[1];
  const float* ea = (const float*)d_in[2];
  const float* W1 = (const float*)d_in[3];
  const float* root1 = (const float*)d_in[4];
  const float* b1 = (const float*)d_in[5];
  const float* W2 = (const float*)d_in[6];
  const float* root2 = (const float*)d_in[7];
  const float* b2 = (const float*)d_in[8];
  const float* Wm = (const float*)d_in[9];
  const float* bm = (const float*)d_in[10];
  const int N = in_sizes[0] / 128;
  const int E = in_sizes[2];
  const int KT1 = 512, KT2 = 768;
  const int nb = cdiv(N, 1024);

  char* base = (char*)d_ws;
  size_t off = 0;
  auto alloc = [&](size_t bytes) -> void* {
    void* p = base + off;
    off += (bytes + 255) & ~(size_t)255;
    return p;
  };
  int* cnt = (int*)alloc((size_t)N * 4);
  int* rowptr = (int*)alloc((size_t)(N + 1) * 4);
  int* cursor = (int*)alloc((size_t)N * 4);
  int* partials = (int*)alloc(256 * 4);
  int* pscan = (int*)alloc(257 * 4);
  int2* es = (int2*)alloc((size_t)E * 8);
  unsigned short* xb = (unsigned short*)alloc((size_t)N * 128 * 2);
  unsigned short* h1 = (unsigned short*)alloc((size_t)N * 128 * 2);
  unsigned short* BtF1 = (unsigned short*)alloc((size_t)128 * KT1 * 2);
  unsigned short* BtF2 = (unsigned short*)alloc((size_t)128 * KT2 * 2);
  (void)ws_size; (void)n_in; (void)out_size;

  // CSR build (dst bins)
  hipMemsetAsync(cnt, 0, (size_t)N * 4, stream);
  hist_kernel<<<cdiv(E, 256), 256, 0, stream>>>(ei, E, cnt);
  scan_partials_kernel<<<nb, 256, 0, stream>>>(cnt, N, partials);
  scan_pscan_kernel<<<1, 256, 0, stream>>>(partials, nb, pscan);
  scan_apply_kernel<<<nb, 256, 0, stream>>>(cnt, N, pscan, nb, rowptr, cursor);
  scatter_kernel<<<cdiv(E, 256), 256, 0, stream>>>(ei, ea, E, cursor, es);

  // weights -> fragment-order bf16
  build_btf_kernel<<<cdiv(128 * KT1, 256), 256, 0, stream>>>(W1, root1, BtF1, 384, KT1);
  build_btf_kernel<<<cdiv(128 * KT2, 256), 256, 0, stream>>>(W2, root2, BtF2, 640, KT2);

  // x -> compact bf16 xb
  cvt_x_kernel<<<2048, 256, 0, stream>>>(x, xb, N * 32);

  const int nblk = cdiv(N, 32);
  // layer 1 (K=3): fused agg+GEMM -> compact h1
  fused_layer<3, 512, false><<<nblk, 256, 0, stream>>>(
      xb, rowptr, es, BtF1, b1, h1, nullptr, nullptr, nullptr, N);
  // layer 2 (K=5): fused agg+GEMM+head -> out
  fused_layer<5, 768, true><<<nblk, 256, 0, stream>>>(
      h1, rowptr, es, BtF2, b2, nullptr, Wm, bm, (float*)d_out, N);
}